// Round 19
// baseline (295.067 us; speedup 1.0000x reference)
//
#include <hip/hip_runtime.h>
#include <cstdint>
#include <cmath>

#define B_    16
#define S_    1024
#define H_    32
#define D_    128
#define HID   4096
#define INTER 11008
#define NC    16        // attention sequence chunks
#define CHUNK 64        // S_/NC
#define TILE  16        // K/V rows per staged tile (single-wave block)

typedef float f32x2 __attribute__((ext_vector_type(2)));
typedef float f32x4 __attribute__((ext_vector_type(4)));

// ---------------------------------------------------------------- RMSNorm
__global__ __launch_bounds__(256) void rmsnorm_kernel(
    const float* __restrict__ in, const float* __restrict__ w, float* __restrict__ out)
{
    int b = blockIdx.x;
    int t = threadIdx.x;
    const float4* row = reinterpret_cast<const float4*>(in + (size_t)b * HID);
    float s = 0.f;
    for (int i = t; i < HID / 4; i += 256) {
        float4 v = row[i];
        s += v.x * v.x + v.y * v.y + v.z * v.z + v.w * v.w;
    }
    for (int off = 32; off; off >>= 1) s += __shfl_down(s, off, 64);
    __shared__ float red[4];
    int wid = t >> 6, lane = t & 63;
    if (lane == 0) red[wid] = s;
    __syncthreads();
    float tot = red[0] + red[1] + red[2] + red[3];
    float rstd = rsqrtf(tot / (float)HID + 1e-6f);
    const float4* wv4 = reinterpret_cast<const float4*>(w);
    float4* o4 = reinterpret_cast<float4*>(out + (size_t)b * HID);
    for (int i = t; i < HID / 4; i += 256) {
        float4 x = row[i], wv = wv4[i];
        float4 r;
        r.x = x.x * rstd * wv.x;
        r.y = x.y * rstd * wv.y;
        r.z = x.z * rstd * wv.z;
        r.w = x.w * rstd * wv.w;
        o4[i] = r;
    }
}

// ------------- skinny GEMM, split-K, float2 cols, register double-buffer
// (frozen R17 configuration: nontemporal weight loads keep partials/x in L2)
__global__ __launch_bounds__(256) void gemm16_splitk2(
    const float* __restrict__ x, const float* __restrict__ w,
    float* __restrict__ part, int K, int N, int kchunk)
{
    int j0 = (blockIdx.x * 256 + threadIdx.x) * 2;
    int k0 = blockIdx.y * kchunk;
    int k1 = k0 + kchunk;
    f32x2 acc[B_];
#pragma unroll
    for (int b = 0; b < B_; ++b) acc[b] = (f32x2)(0.f, 0.f);

    const float* wp = w + (size_t)k0 * N + j0;
    f32x2 wv[8];
#pragma unroll
    for (int i = 0; i < 8; ++i)                    // prologue: first 8 rows
        wv[i] = __builtin_nontemporal_load(
            reinterpret_cast<const f32x2*>(wp + (size_t)i * N));
    wp += 8 * (size_t)N;

    for (int k = k0; k < k1 - 8; k += 8) {
        f32x2 wn[8];
#pragma unroll
        for (int i = 0; i < 8; ++i)                // issue next tile's nt loads
            wn[i] = __builtin_nontemporal_load(
                reinterpret_cast<const f32x2*>(wp + (size_t)i * N));
        wp += 8 * (size_t)N;
#pragma unroll
        for (int b = 0; b < B_; ++b) {             // FMA on current tile
            const float* xb = x + (size_t)b * K + k;   // wave-uniform -> s_load
#pragma unroll
            for (int i = 0; i < 8; ++i) {
                float xv = xb[i];
                acc[b].x = fmaf(xv, wv[i].x, acc[b].x);
                acc[b].y = fmaf(xv, wv[i].y, acc[b].y);
            }
        }
#pragma unroll
        for (int i = 0; i < 8; ++i) wv[i] = wn[i]; // rotate
    }
    {   // epilogue: FMA on the last tile (k = k1-8)
        int k = k1 - 8;
#pragma unroll
        for (int b = 0; b < B_; ++b) {
            const float* xb = x + (size_t)b * K + k;
#pragma unroll
            for (int i = 0; i < 8; ++i) {
                float xv = xb[i];
                acc[b].x = fmaf(xv, wv[i].x, acc[b].x);
                acc[b].y = fmaf(xv, wv[i].y, acc[b].y);
            }
        }
    }
    float* pp = part + (size_t)blockIdx.y * B_ * N + j0;
#pragma unroll
    for (int b = 0; b < B_; ++b) {
        pp[(size_t)b * N]     = acc[b].x;          // normal stores: keep in L2
        pp[(size_t)b * N + 1] = acc[b].y;
    }
}

// -------------------------------------------- reduce partials + bias + residual
__global__ __launch_bounds__(256) void reduce_bias_res(
    const float* __restrict__ part, int nsplit, int N,
    const float* __restrict__ bias, const float* __restrict__ res,
    float* __restrict__ out, int total)
{
    int i = blockIdx.x * 256 + threadIdx.x;
    if (i >= total) return;
    float s = 0.f;
    for (int p = 0; p < nsplit; ++p) s += part[(size_t)p * total + i];
    int jc = i % N;
    if (bias) s += bias[jc];
    if (res)  s += res[i];
    out[i] = s;
}

// --------------------------- fused QKV reduce + bias + RoPE (NeoX) + scatter
__global__ __launch_bounds__(256) void qkv_reduce_rope(
    const float* __restrict__ part, int nsplit, const float* __restrict__ bias,
    const int* __restrict__ positions,
    float* __restrict__ q_rot, float* __restrict__ k_rot, float* __restrict__ v_cp)
{
    int b = blockIdx.y;
    int t = threadIdx.x;
    int col = blockIdx.x * 256 + t;
    const int total = B_ * 3 * HID;
    size_t idx = (size_t)b * (3 * HID) + col;
    float s = 0.f;
    for (int p = 0; p < nsplit; ++p) s += part[(size_t)p * total + idx];
    s += bias[col];
    __shared__ float ls[256];
    ls[t] = s;
    __syncthreads();
    int region = col >> 12;          // 0=q, 1=k, 2=v  (HID=4096)
    float outv;
    if (region < 2) {
        int d = col & 127;
        float partner = ls[t ^ 64];  // same head: block base is 256-aligned
        float pos = (float)positions[b];
        float freq = powf(10000.0f, -(float)(d & 63) / 64.0f);
        float sv, cv;
        sincosf(pos * freq, &sv, &cv);
        outv = (d < 64) ? (s * cv - partner * sv) : (s * cv + partner * sv);
    } else {
        outv = s;
    }
    float* dst = (region == 0) ? q_rot : (region == 1) ? k_rot : v_cp;
    dst[(size_t)b * HID + (col & 4095)] = outv;
}

// ------------------------------------- reduce partials of gate_up + fused SwiGLU
__global__ __launch_bounds__(256) void reduce_silu(
    const float* __restrict__ part, int nsplit, float* __restrict__ act)
{
    int i = blockIdx.x * 256 + threadIdx.x;
    if (i >= B_ * INTER) return;
    int b = i / INTER;
    int jc = i - b * INTER;
    size_t off = (size_t)b * (2 * INTER) + jc;
    float g = 0.f, u = 0.f;
    for (int p = 0; p < nsplit; ++p) {
        const float* pp = part + (size_t)p * B_ * 2 * INTER;
        g += pp[off];
        u += pp[off + INTER];
    }
    float sg = g / (1.f + expf(-g));
    act[i] = sg * u;
}

// --------------------------------------------------- split-S decode attention
// (R18 body; single change: K/V staging loads are NONTEMPORAL — the cache
// rows are single-use streams (NC chunks partition rows disjointly per (b,h)),
// so bypassing L2 retention keeps pacc/q_rot/k_rot/v_cp resident for combine.)
__global__ __launch_bounds__(64) void attn_split(
    const float* __restrict__ kc, const float* __restrict__ vc,
    const float* __restrict__ q_rot, const float* __restrict__ k_rot,
    const float* __restrict__ v_cp, const int* __restrict__ positions,
    float* __restrict__ pacc, float* __restrict__ pm, float* __restrict__ pl)
{
    int h = blockIdx.x, b = blockIdx.y, c = blockIdx.z, t = threadIdx.x; // t in [0,64)
    int pos = positions[b];
    int L = pos + 1;
    int j0c = c * CHUNK;
    size_t pidx = (((size_t)b * H_ + h) * NC + c);
    if (j0c >= L) {                 // empty chunk: deterministic zero partials
        if (t == 0) { pm[pidx] = -INFINITY; pl[pidx] = 0.f; }
        pacc[pidx * D_ + t] = 0.f;
        pacc[pidx * D_ + t + 64] = 0.f;
        return;
    }
    int jend = min(L, j0c + CHUNK);
    int jr = t >> 2, q4 = t & 3;    // 4 lanes per key row, 16 rows

    __shared__ float qs[D_];
    __shared__ float ks[TILE * 132];  // padded stride (score reads 2 lanes/bank)
    __shared__ float vs[TILE * D_];
    __shared__ float sc[TILE];

    size_t bh = ((size_t)b * H_ + h) * D_;
    qs[t] = q_rot[bh + t];
    qs[t + 64] = q_rot[bh + t + 64];

    float m = -INFINITY, l = 0.f, a0 = 0.f, a1 = 0.f;
    const float scaling = 0.08838834764831845f;  // 128^-0.5

    for (int j0 = j0c; j0 < jend; j0 += TILE) {
        int nj = min(TILE, jend - j0);
        bool hasPos = (pos >= j0) && (pos < j0 + TILE);
        int rpos = pos - j0;
        __syncthreads();            // single-wave: waitcnt only
        // stage K+V: 16 rows x 32 float4 each; branch-free, NONTEMPORAL
#pragma unroll
        for (int rep = 0; rep < 8; ++rep) {
            int idx = rep * 64 + t;
            int r = idx >> 5, c4 = idx & 31;
            size_t rowoff = (((size_t)b * S_ + (j0 + r)) * H_ + h) * D_;
            f32x4 kv = __builtin_nontemporal_load(
                reinterpret_cast<const f32x4*>(kc + rowoff) + c4);
            f32x4 vv = __builtin_nontemporal_load(
                reinterpret_cast<const f32x4*>(vc + rowoff) + c4);
            *reinterpret_cast<f32x4*>(&ks[r * 132 + c4 * 4]) = kv;
            *reinterpret_cast<f32x4*>(&vs[r * D_  + c4 * 4]) = vv;
        }
        if (hasPos) {               // override pos row from k_rot / v_cp
            if (t < 32) {
                float4 kv = reinterpret_cast<const float4*>(k_rot + bh)[t];
                *reinterpret_cast<float4*>(&ks[rpos * 132 + t * 4]) = kv;
            } else {
                int c4 = t - 32;
                float4 vv = reinterpret_cast<const float4*>(v_cp + bh)[c4];
                *reinterpret_cast<float4*>(&vs[rpos * D_ + c4 * 4]) = vv;
            }
        }
        __syncthreads();
        // scores: stride-4 interleaved dims; K read 2 lanes/bank, Q broadcast
        {
            const float* kr = ks + jr * 132 + q4;
            float s = 0.f;
#pragma unroll
            for (int ci = 0; ci < 32; ++ci) s = fmaf(qs[q4 + 4 * ci], kr[4 * ci], s);
            s += __shfl_xor(s, 1, 64);
            s += __shfl_xor(s, 2, 64);
            if (q4 == 0) sc[jr] = s * scaling;
        }
        __syncthreads();
        // online softmax (registers, static indexing only)
        float p[TILE];
        float mt = m;
#pragma unroll
        for (int r = 0; r < TILE; ++r) {
            float v = (r < nj) ? sc[r] : -INFINITY;
            p[r] = v;
            mt = fmaxf(mt, v);
        }
        float scale = expf(m - mt);
        float ps = 0.f;
#pragma unroll
        for (int r = 0; r < TILE; ++r) {
            float e = (r < nj) ? expf(p[r] - mt) : 0.f;
            p[r] = e;
            ps += e;
        }
        m = mt;
        l = l * scale + ps;
        a0 *= scale;
        a1 *= scale;
#pragma unroll
        for (int r = 0; r < TILE; ++r) {
            a0 = fmaf(p[r], vs[r * D_ + t], a0);
            a1 = fmaf(p[r], vs[r * D_ + t + 64], a1);
        }
    }
    pm[pidx] = m;
    pl[pidx] = l;
    pacc[pidx * D_ + t] = a0;
    pacc[pidx * D_ + t + 64] = a1;
}

// ------------------------------------------------------- combine chunk partials
__global__ __launch_bounds__(128) void attn_combine(
    const float* __restrict__ pacc, const float* __restrict__ pm,
    const float* __restrict__ pl, float* __restrict__ out)
{
    int h = blockIdx.x, b = blockIdx.y, t = threadIdx.x;
    size_t base = ((size_t)b * H_ + h) * NC;
    float M = -INFINITY;
#pragma unroll
    for (int c = 0; c < NC; ++c) M = fmaxf(M, pm[base + c]);
    float l = 0.f, a = 0.f;
#pragma unroll
    for (int c = 0; c < NC; ++c) {
        float w = expf(pm[base + c] - M);
        l = fmaf(pl[base + c], w, l);
        a = fmaf(pacc[(base + c) * D_ + t], w, a);
    }
    out[((size_t)b * H_ + h) * D_ + t] = a / l;
}

// ---------------------------------------------------------------- launcher
extern "C" void kernel_launch(void* const* d_in, const int* in_sizes, int n_in,
                              void* d_out, int out_size, void* d_ws, size_t ws_size,
                              hipStream_t stream)
{
    const int*   positions = (const int*)  d_in[0];
    const float* hidden    = (const float*)d_in[1];
    const float* kc        = (const float*)d_in[2];
    const float* vc        = (const float*)d_in[3];
    const float* qkv_w     = (const float*)d_in[4];
    const float* qkv_b     = (const float*)d_in[5];
    const float* o_w       = (const float*)d_in[6];
    const float* o_b       = (const float*)d_in[7];
    const float* gu_w      = (const float*)d_in[8];
    const float* down_w    = (const float*)d_in[9];
    const float* ln1       = (const float*)d_in[10];
    const float* ln2       = (const float*)d_in[11];
    float* out = (float*)d_out;
    float* ws  = (float*)d_ws;

    float* x1      = ws;                             // 16*4096
    float* q_rot   = x1 + (size_t)B_ * HID;
    float* k_rot   = q_rot + (size_t)B_ * HID;
    float* v_cp    = k_rot + (size_t)B_ * HID;
    float* attn_o  = v_cp + (size_t)B_ * HID;
    float* hidden2 = attn_o + (size_t)B_ * HID;
    float* x2      = hidden2 + (size_t)B_ * HID;
    float* act     = x2 + (size_t)B_ * HID;          // 16*11008
    float* part    = act + (size_t)B_ * INTER;       // partials region

    float* pacc = part;                              // attention overlay (4 MB)
    float* pm   = pacc + (size_t)B_ * H_ * NC * D_;
    float* pl   = pm + (size_t)B_ * H_ * NC;

    // 1. RMSNorm 1
    rmsnorm_kernel<<<B_, 256, 0, stream>>>(hidden, ln1, x1);
    // 2. QKV GEMM (K=4096, N=12288): 24 col-blocks x 32 k-splits (kchunk=128)
    gemm16_splitk2<<<dim3(24, 32), 256, 0, stream>>>(x1, qkv_w, part, HID, 3 * HID, 128);
    // 3. fused reduce + bias + RoPE scatter
    qkv_reduce_rope<<<dim3(48, B_), 256, 0, stream>>>(part, 32, qkv_b, positions,
                                                      q_rot, k_rot, v_cp);
    // 4. split-S decode attention (single-wave blocks, NC=16) + combine
    attn_split<<<dim3(H_, B_, NC), 64, 0, stream>>>(kc, vc, q_rot, k_rot, v_cp, positions,
                                                    pacc, pm, pl);
    attn_combine<<<dim3(H_, B_), 128, 0, stream>>>(pacc, pm, pl, attn_o);
    // 5. O proj (K=4096, N=4096): 8 x 64 (kchunk=64), + residual
    gemm16_splitk2<<<dim3(8, 64), 256, 0, stream>>>(attn_o, o_w, part, HID, HID, 64);
    reduce_bias_res<<<256, 256, 0, stream>>>(part, 64, HID, o_b, hidden, hidden2, B_ * HID);
    // 6. RMSNorm 2
    rmsnorm_kernel<<<B_, 256, 0, stream>>>(hidden2, ln2, x2);
    // 7. gate_up GEMM (K=4096, N=22016): 43 x 16 (kchunk=256), + fused SwiGLU reduce
    gemm16_splitk2<<<dim3(43, 16), 256, 0, stream>>>(x2, gu_w, part, HID, 2 * INTER, 256);
    reduce_silu<<<688, 256, 0, stream>>>(part, 16, act);
    // 8. down GEMM (K=11008, N=4096): 8 x 43 (kchunk=256), + residual -> out
    gemm16_splitk2<<<dim3(8, 43), 256, 0, stream>>>(act, down_w, part, INTER, HID, 256);
    reduce_bias_res<<<256, 256, 0, stream>>>(part, 43, HID, nullptr, hidden2, out, B_ * HID);
}

// Round 20
// 294.060 us; speedup vs baseline: 1.0034x; 1.0034x over previous
//
#include <hip/hip_runtime.h>
#include <cstdint>
#include <cmath>

#define B_    16
#define S_    1024
#define H_    32
#define D_    128
#define HID   4096
#define INTER 11008
#define NC    16        // attention sequence chunks
#define CHUNK 64        // S_/NC
#define TILE  16        // K/V rows per staged tile (single-wave block)

typedef float f32x2 __attribute__((ext_vector_type(2)));

// ---------------------------------------------------------------- RMSNorm
__global__ __launch_bounds__(256) void rmsnorm_kernel(
    const float* __restrict__ in, const float* __restrict__ w, float* __restrict__ out)
{
    int b = blockIdx.x;
    int t = threadIdx.x;
    const float4* row = reinterpret_cast<const float4*>(in + (size_t)b * HID);
    float s = 0.f;
    for (int i = t; i < HID / 4; i += 256) {
        float4 v = row[i];
        s += v.x * v.x + v.y * v.y + v.z * v.z + v.w * v.w;
    }
    for (int off = 32; off; off >>= 1) s += __shfl_down(s, off, 64);
    __shared__ float red[4];
    int wid = t >> 6, lane = t & 63;
    if (lane == 0) red[wid] = s;
    __syncthreads();
    float tot = red[0] + red[1] + red[2] + red[3];
    float rstd = rsqrtf(tot / (float)HID + 1e-6f);
    const float4* wv4 = reinterpret_cast<const float4*>(w);
    float4* o4 = reinterpret_cast<float4*>(out + (size_t)b * HID);
    for (int i = t; i < HID / 4; i += 256) {
        float4 x = row[i], wv = wv4[i];
        float4 r;
        r.x = x.x * rstd * wv.x;
        r.y = x.y * rstd * wv.y;
        r.z = x.z * rstd * wv.z;
        r.w = x.w * rstd * wv.w;
        o4[i] = r;
    }
}

// ------------- skinny GEMM, split-K, float2 cols, register double-buffer
// (frozen R17 configuration: nontemporal weight loads keep partials/x in L2)
__global__ __launch_bounds__(256) void gemm16_splitk2(
    const float* __restrict__ x, const float* __restrict__ w,
    float* __restrict__ part, int K, int N, int kchunk)
{
    int j0 = (blockIdx.x * 256 + threadIdx.x) * 2;
    int k0 = blockIdx.y * kchunk;
    int k1 = k0 + kchunk;
    f32x2 acc[B_];
#pragma unroll
    for (int b = 0; b < B_; ++b) acc[b] = (f32x2)(0.f, 0.f);

    const float* wp = w + (size_t)k0 * N + j0;
    f32x2 wv[8];
#pragma unroll
    for (int i = 0; i < 8; ++i)                    // prologue: first 8 rows
        wv[i] = __builtin_nontemporal_load(
            reinterpret_cast<const f32x2*>(wp + (size_t)i * N));
    wp += 8 * (size_t)N;

    for (int k = k0; k < k1 - 8; k += 8) {
        f32x2 wn[8];
#pragma unroll
        for (int i = 0; i < 8; ++i)                // issue next tile's nt loads
            wn[i] = __builtin_nontemporal_load(
                reinterpret_cast<const f32x2*>(wp + (size_t)i * N));
        wp += 8 * (size_t)N;
#pragma unroll
        for (int b = 0; b < B_; ++b) {             // FMA on current tile
            const float* xb = x + (size_t)b * K + k;   // wave-uniform -> s_load
#pragma unroll
            for (int i = 0; i < 8; ++i) {
                float xv = xb[i];
                acc[b].x = fmaf(xv, wv[i].x, acc[b].x);
                acc[b].y = fmaf(xv, wv[i].y, acc[b].y);
            }
        }
#pragma unroll
        for (int i = 0; i < 8; ++i) wv[i] = wn[i]; // rotate
    }
    {   // epilogue: FMA on the last tile (k = k1-8)
        int k = k1 - 8;
#pragma unroll
        for (int b = 0; b < B_; ++b) {
            const float* xb = x + (size_t)b * K + k;
#pragma unroll
            for (int i = 0; i < 8; ++i) {
                float xv = xb[i];
                acc[b].x = fmaf(xv, wv[i].x, acc[b].x);
                acc[b].y = fmaf(xv, wv[i].y, acc[b].y);
            }
        }
    }
    float* pp = part + (size_t)blockIdx.y * B_ * N + j0;
#pragma unroll
    for (int b = 0; b < B_; ++b) {
        pp[(size_t)b * N]     = acc[b].x;          // normal stores: keep in L2
        pp[(size_t)b * N + 1] = acc[b].y;
    }
}

// -------------------------------------------- reduce partials + bias + residual
__global__ __launch_bounds__(256) void reduce_bias_res(
    const float* __restrict__ part, int nsplit, int N,
    const float* __restrict__ bias, const float* __restrict__ res,
    float* __restrict__ out, int total)
{
    int i = blockIdx.x * 256 + threadIdx.x;
    if (i >= total) return;
    float s = 0.f;
    for (int p = 0; p < nsplit; ++p) s += part[(size_t)p * total + i];
    int jc = i % N;
    if (bias) s += bias[jc];
    if (res)  s += res[i];
    out[i] = s;
}

// --------------------------- fused QKV reduce + bias + RoPE (NeoX) + scatter
__global__ __launch_bounds__(256) void qkv_reduce_rope(
    const float* __restrict__ part, int nsplit, const float* __restrict__ bias,
    const int* __restrict__ positions,
    float* __restrict__ q_rot, float* __restrict__ k_rot, float* __restrict__ v_cp)
{
    int b = blockIdx.y;
    int t = threadIdx.x;
    int col = blockIdx.x * 256 + t;
    const int total = B_ * 3 * HID;
    size_t idx = (size_t)b * (3 * HID) + col;
    float s = 0.f;
    for (int p = 0; p < nsplit; ++p) s += part[(size_t)p * total + idx];
    s += bias[col];
    __shared__ float ls[256];
    ls[t] = s;
    __syncthreads();
    int region = col >> 12;          // 0=q, 1=k, 2=v  (HID=4096)
    float outv;
    if (region < 2) {
        int d = col & 127;
        float partner = ls[t ^ 64];  // same head: block base is 256-aligned
        float pos = (float)positions[b];
        float freq = powf(10000.0f, -(float)(d & 63) / 64.0f);
        float sv, cv;
        sincosf(pos * freq, &sv, &cv);
        outv = (d < 64) ? (s * cv - partner * sv) : (s * cv + partner * sv);
    } else {
        outv = s;
    }
    float* dst = (region == 0) ? q_rot : (region == 1) ? k_rot : v_cp;
    dst[(size_t)b * HID + (col & 4095)] = outv;
}

// ------------------------------------- reduce partials of gate_up + fused SwiGLU
__global__ __launch_bounds__(256) void reduce_silu(
    const float* __restrict__ part, int nsplit, float* __restrict__ act)
{
    int i = blockIdx.x * 256 + threadIdx.x;
    if (i >= B_ * INTER) return;
    int b = i / INTER;
    int jc = i - b * INTER;
    size_t off = (size_t)b * (2 * INTER) + jc;
    float g = 0.f, u = 0.f;
    for (int p = 0; p < nsplit; ++p) {
        const float* pp = part + (size_t)p * B_ * 2 * INTER;
        g += pp[off];
        u += pp[off + INTER];
    }
    float sg = g / (1.f + expf(-g));
    act[i] = sg * u;
}

// --------------------------------------------------- split-S decode attention
// (frozen R18 configuration: single-wave 64-thread block per (h,b,chunk),
// NC=16/CHUNK=64, synchronous float4 staging, stride-4 interleaved score reads)
__global__ __launch_bounds__(64) void attn_split(
    const float* __restrict__ kc, const float* __restrict__ vc,
    const float* __restrict__ q_rot, const float* __restrict__ k_rot,
    const float* __restrict__ v_cp, const int* __restrict__ positions,
    float* __restrict__ pacc, float* __restrict__ pm, float* __restrict__ pl)
{
    int h = blockIdx.x, b = blockIdx.y, c = blockIdx.z, t = threadIdx.x; // t in [0,64)
    int pos = positions[b];
    int L = pos + 1;
    int j0c = c * CHUNK;
    size_t pidx = (((size_t)b * H_ + h) * NC + c);
    if (j0c >= L) {                 // empty chunk: deterministic zero partials
        if (t == 0) { pm[pidx] = -INFINITY; pl[pidx] = 0.f; }
        pacc[pidx * D_ + t] = 0.f;
        pacc[pidx * D_ + t + 64] = 0.f;
        return;
    }
    int jend = min(L, j0c + CHUNK);
    int jr = t >> 2, q4 = t & 3;    // 4 lanes per key row, 16 rows

    __shared__ float qs[D_];
    __shared__ float ks[TILE * 132];  // padded stride (score reads 2 lanes/bank)
    __shared__ float vs[TILE * D_];
    __shared__ float sc[TILE];

    size_t bh = ((size_t)b * H_ + h) * D_;
    qs[t] = q_rot[bh + t];
    qs[t + 64] = q_rot[bh + t + 64];

    float m = -INFINITY, l = 0.f, a0 = 0.f, a1 = 0.f;
    const float scaling = 0.08838834764831845f;  // 128^-0.5

    for (int j0 = j0c; j0 < jend; j0 += TILE) {
        int nj = min(TILE, jend - j0);
        bool hasPos = (pos >= j0) && (pos < j0 + TILE);
        int rpos = pos - j0;
        __syncthreads();            // single-wave: waitcnt only
        // stage K+V: 16 rows x 32 float4 each; branch-free (rows always < S)
#pragma unroll
        for (int rep = 0; rep < 8; ++rep) {
            int idx = rep * 64 + t;
            int r = idx >> 5, c4 = idx & 31;
            size_t rowoff = (((size_t)b * S_ + (j0 + r)) * H_ + h) * D_;
            float4 kv = reinterpret_cast<const float4*>(kc + rowoff)[c4];
            float4 vv = reinterpret_cast<const float4*>(vc + rowoff)[c4];
            *reinterpret_cast<float4*>(&ks[r * 132 + c4 * 4]) = kv;
            *reinterpret_cast<float4*>(&vs[r * D_  + c4 * 4]) = vv;
        }
        if (hasPos) {               // override pos row from k_rot / v_cp
            if (t < 32) {
                float4 kv = reinterpret_cast<const float4*>(k_rot + bh)[t];
                *reinterpret_cast<float4*>(&ks[rpos * 132 + t * 4]) = kv;
            } else {
                int c4 = t - 32;
                float4 vv = reinterpret_cast<const float4*>(v_cp + bh)[c4];
                *reinterpret_cast<float4*>(&vs[rpos * D_ + c4 * 4]) = vv;
            }
        }
        __syncthreads();
        // scores: stride-4 interleaved dims; K read 2 lanes/bank, Q broadcast
        {
            const float* kr = ks + jr * 132 + q4;
            float s = 0.f;
#pragma unroll
            for (int ci = 0; ci < 32; ++ci) s = fmaf(qs[q4 + 4 * ci], kr[4 * ci], s);
            s += __shfl_xor(s, 1, 64);
            s += __shfl_xor(s, 2, 64);
            if (q4 == 0) sc[jr] = s * scaling;
        }
        __syncthreads();
        // online softmax (registers, static indexing only)
        float p[TILE];
        float mt = m;
#pragma unroll
        for (int r = 0; r < TILE; ++r) {
            float v = (r < nj) ? sc[r] : -INFINITY;
            p[r] = v;
            mt = fmaxf(mt, v);
        }
        float scale = expf(m - mt);
        float ps = 0.f;
#pragma unroll
        for (int r = 0; r < TILE; ++r) {
            float e = (r < nj) ? expf(p[r] - mt) : 0.f;
            p[r] = e;
            ps += e;
        }
        m = mt;
        l = l * scale + ps;
        a0 *= scale;
        a1 *= scale;
#pragma unroll
        for (int r = 0; r < TILE; ++r) {
            a0 = fmaf(p[r], vs[r * D_ + t], a0);
            a1 = fmaf(p[r], vs[r * D_ + t + 64], a1);
        }
    }
    pm[pidx] = m;
    pl[pidx] = l;
    pacc[pidx * D_ + t] = a0;
    pacc[pidx * D_ + t + 64] = a1;
}

// ------------------------------------------------------- combine chunk partials
__global__ __launch_bounds__(128) void attn_combine(
    const float* __restrict__ pacc, const float* __restrict__ pm,
    const float* __restrict__ pl, float* __restrict__ out)
{
    int h = blockIdx.x, b = blockIdx.y, t = threadIdx.x;
    size_t base = ((size_t)b * H_ + h) * NC;
    float M = -INFINITY;
#pragma unroll
    for (int c = 0; c < NC; ++c) M = fmaxf(M, pm[base + c]);
    float l = 0.f, a = 0.f;
#pragma unroll
    for (int c = 0; c < NC; ++c) {
        float w = expf(pm[base + c] - M);
        l = fmaf(pl[base + c], w, l);
        a = fmaf(pacc[(base + c) * D_ + t], w, a);
    }
    out[((size_t)b * H_ + h) * D_ + t] = a / l;
}

// ---------------------------------------------------------------- launcher
extern "C" void kernel_launch(void* const* d_in, const int* in_sizes, int n_in,
                              void* d_out, int out_size, void* d_ws, size_t ws_size,
                              hipStream_t stream)
{
    const int*   positions = (const int*)  d_in[0];
    const float* hidden    = (const float*)d_in[1];
    const float* kc        = (const float*)d_in[2];
    const float* vc        = (const float*)d_in[3];
    const float* qkv_w     = (const float*)d_in[4];
    const float* qkv_b     = (const float*)d_in[5];
    const float* o_w       = (const float*)d_in[6];
    const float* o_b       = (const float*)d_in[7];
    const float* gu_w      = (const float*)d_in[8];
    const float* down_w    = (const float*)d_in[9];
    const float* ln1       = (const float*)d_in[10];
    const float* ln2       = (const float*)d_in[11];
    float* out = (float*)d_out;
    float* ws  = (float*)d_ws;

    float* x1      = ws;                             // 16*4096
    float* q_rot   = x1 + (size_t)B_ * HID;
    float* k_rot   = q_rot + (size_t)B_ * HID;
    float* v_cp    = k_rot + (size_t)B_ * HID;
    float* attn_o  = v_cp + (size_t)B_ * HID;
    float* hidden2 = attn_o + (size_t)B_ * HID;
    float* x2      = hidden2 + (size_t)B_ * HID;
    float* act     = x2 + (size_t)B_ * HID;          // 16*11008
    float* part    = act + (size_t)B_ * INTER;       // partials region

    float* pacc = part;                              // attention overlay (4 MB)
    float* pm   = pacc + (size_t)B_ * H_ * NC * D_;
    float* pl   = pm + (size_t)B_ * H_ * NC;

    // 1. RMSNorm 1
    rmsnorm_kernel<<<B_, 256, 0, stream>>>(hidden, ln1, x1);
    // 2. QKV GEMM (K=4096, N=12288): 24 col-blocks x 32 k-splits (kchunk=128)
    gemm16_splitk2<<<dim3(24, 32), 256, 0, stream>>>(x1, qkv_w, part, HID, 3 * HID, 128);
    // 3. fused reduce + bias + RoPE scatter
    qkv_reduce_rope<<<dim3(48, B_), 256, 0, stream>>>(part, 32, qkv_b, positions,
                                                      q_rot, k_rot, v_cp);
    // 4. split-S decode attention (single-wave blocks, NC=16) + combine
    attn_split<<<dim3(H_, B_, NC), 64, 0, stream>>>(kc, vc, q_rot, k_rot, v_cp, positions,
                                                    pacc, pm, pl);
    attn_combine<<<dim3(H_, B_), 128, 0, stream>>>(pacc, pm, pl, attn_o);
    // 5. O proj (K=4096, N=4096): 8 x 64 (kchunk=64), + residual
    gemm16_splitk2<<<dim3(8, 64), 256, 0, stream>>>(attn_o, o_w, part, HID, HID, 64);
    reduce_bias_res<<<256, 256, 0, stream>>>(part, 64, HID, o_b, hidden, hidden2, B_ * HID);
    // 6. RMSNorm 2
    rmsnorm_kernel<<<B_, 256, 0, stream>>>(hidden2, ln2, x2);
    // 7. gate_up GEMM (K=4096, N=22016): 43 x 16 (kchunk=256), + fused SwiGLU reduce
    gemm16_splitk2<<<dim3(43, 16), 256, 0, stream>>>(x2, gu_w, part, HID, 2 * INTER, 256);
    reduce_silu<<<688, 256, 0, stream>>>(part, 16, act);
    // 8. down GEMM (K=11008, N=4096): 8 x 43 (kchunk=256), + residual -> out
    gemm16_splitk2<<<dim3(8, 43), 256, 0, stream>>>(act, down_w, part, INTER, HID, 256);
    reduce_bias_res<<<256, 256, 0, stream>>>(part, 43, HID, nullptr, hidden2, out, B_ * HID);
}

// Round 21
// 288.392 us; speedup vs baseline: 1.0231x; 1.0197x over previous
//
#include <hip/hip_runtime.h>
#include <cstdint>
#include <cmath>

#define B_    16
#define S_    1024
#define H_    32
#define D_    128
#define HID   4096
#define INTER 11008
#define NC    16        // attention sequence chunks
#define CHUNK 64        // S_/NC
#define TILE  16        // K/V rows per staged tile (single-wave block)

typedef float f32x2 __attribute__((ext_vector_type(2)));
typedef float f32x4 __attribute__((ext_vector_type(4)));

// ---------------------------------------------------------------- RMSNorm
__global__ __launch_bounds__(256) void rmsnorm_kernel(
    const float* __restrict__ in, const float* __restrict__ w, float* __restrict__ out)
{
    int b = blockIdx.x;
    int t = threadIdx.x;
    const float4* row = reinterpret_cast<const float4*>(in + (size_t)b * HID);
    float s = 0.f;
    for (int i = t; i < HID / 4; i += 256) {
        float4 v = row[i];
        s += v.x * v.x + v.y * v.y + v.z * v.z + v.w * v.w;
    }
    for (int off = 32; off; off >>= 1) s += __shfl_down(s, off, 64);
    __shared__ float red[4];
    int wid = t >> 6, lane = t & 63;
    if (lane == 0) red[wid] = s;
    __syncthreads();
    float tot = red[0] + red[1] + red[2] + red[3];
    float rstd = rsqrtf(tot / (float)HID + 1e-6f);
    const float4* wv4 = reinterpret_cast<const float4*>(w);
    float4* o4 = reinterpret_cast<float4*>(out + (size_t)b * HID);
    for (int i = t; i < HID / 4; i += 256) {
        float4 x = row[i], wv = wv4[i];
        float4 r;
        r.x = x.x * rstd * wv.x;
        r.y = x.y * rstd * wv.y;
        r.z = x.z * rstd * wv.z;
        r.w = x.w * rstd * wv.w;
        o4[i] = r;
    }
}

// ------------- skinny GEMM, split-K, float2 cols, register double-buffer
// (frozen R17 configuration — used for O-proj and down GEMMs)
__global__ __launch_bounds__(256) void gemm16_splitk2(
    const float* __restrict__ x, const float* __restrict__ w,
    float* __restrict__ part, int K, int N, int kchunk)
{
    int j0 = (blockIdx.x * 256 + threadIdx.x) * 2;
    int k0 = blockIdx.y * kchunk;
    int k1 = k0 + kchunk;
    f32x2 acc[B_];
#pragma unroll
    for (int b = 0; b < B_; ++b) acc[b] = (f32x2)(0.f, 0.f);

    const float* wp = w + (size_t)k0 * N + j0;
    f32x2 wv[8];
#pragma unroll
    for (int i = 0; i < 8; ++i)                    // prologue: first 8 rows
        wv[i] = __builtin_nontemporal_load(
            reinterpret_cast<const f32x2*>(wp + (size_t)i * N));
    wp += 8 * (size_t)N;

    for (int k = k0; k < k1 - 8; k += 8) {
        f32x2 wn[8];
#pragma unroll
        for (int i = 0; i < 8; ++i)                // issue next tile's nt loads
            wn[i] = __builtin_nontemporal_load(
                reinterpret_cast<const f32x2*>(wp + (size_t)i * N));
        wp += 8 * (size_t)N;
#pragma unroll
        for (int b = 0; b < B_; ++b) {             // FMA on current tile
            const float* xb = x + (size_t)b * K + k;   // wave-uniform -> s_load
#pragma unroll
            for (int i = 0; i < 8; ++i) {
                float xv = xb[i];
                acc[b].x = fmaf(xv, wv[i].x, acc[b].x);
                acc[b].y = fmaf(xv, wv[i].y, acc[b].y);
            }
        }
#pragma unroll
        for (int i = 0; i < 8; ++i) wv[i] = wn[i]; // rotate
    }
    {   // epilogue: FMA on the last tile (k = k1-8)
        int k = k1 - 8;
#pragma unroll
        for (int b = 0; b < B_; ++b) {
            const float* xb = x + (size_t)b * K + k;
#pragma unroll
            for (int i = 0; i < 8; ++i) {
                float xv = xb[i];
                acc[b].x = fmaf(xv, wv[i].x, acc[b].x);
                acc[b].y = fmaf(xv, wv[i].y, acc[b].y);
            }
        }
    }
    float* pp = part + (size_t)blockIdx.y * B_ * N + j0;
#pragma unroll
    for (int b = 0; b < B_; ++b) {
        pp[(size_t)b * N]     = acc[b].x;          // normal stores: keep in L2
        pp[(size_t)b * N + 1] = acc[b].y;
    }
}

// ------------- skinny GEMM, split-K, FLOAT4 cols, register double-buffer
// Same structure as splitk2 but 16 B/lane loads: halves VMEM instruction count
// and address VALU at equal in-flight bytes/CU. blockDim-parametric so QKV
// (256 thr, 1024-col strips) and gate_up (128 thr, 512-col strips) both map
// exactly (no ragged tail). Requires 4 | N, 16 <= kchunk, 8 | kchunk.
__global__ __launch_bounds__(256) void gemm16_splitk4(
    const float* __restrict__ x, const float* __restrict__ w,
    float* __restrict__ part, int K, int N, int kchunk)
{
    int j0 = (blockIdx.x * blockDim.x + threadIdx.x) * 4;
    if (j0 >= N) return;                           // safety (grids are exact)
    int k0 = blockIdx.y * kchunk;
    int k1 = k0 + kchunk;
    f32x4 acc[B_];
#pragma unroll
    for (int b = 0; b < B_; ++b) acc[b] = (f32x4)(0.f, 0.f, 0.f, 0.f);

    const float* wp = w + (size_t)k0 * N + j0;
    f32x4 wv[8];
#pragma unroll
    for (int i = 0; i < 8; ++i)                    // prologue: first 8 rows
        wv[i] = __builtin_nontemporal_load(
            reinterpret_cast<const f32x4*>(wp + (size_t)i * N));
    wp += 8 * (size_t)N;

    for (int k = k0; k < k1 - 8; k += 8) {
        f32x4 wn[8];
#pragma unroll
        for (int i = 0; i < 8; ++i)                // issue next tile's nt loads
            wn[i] = __builtin_nontemporal_load(
                reinterpret_cast<const f32x4*>(wp + (size_t)i * N));
        wp += 8 * (size_t)N;
#pragma unroll
        for (int b = 0; b < B_; ++b) {             // FMA on current tile
            const float* xb = x + (size_t)b * K + k;   // wave-uniform -> s_load
#pragma unroll
            for (int i = 0; i < 8; ++i) {
                float xv = xb[i];
                acc[b].x = fmaf(xv, wv[i].x, acc[b].x);
                acc[b].y = fmaf(xv, wv[i].y, acc[b].y);
                acc[b].z = fmaf(xv, wv[i].z, acc[b].z);
                acc[b].w = fmaf(xv, wv[i].w, acc[b].w);
            }
        }
#pragma unroll
        for (int i = 0; i < 8; ++i) wv[i] = wn[i]; // rotate
    }
    {   // epilogue: FMA on the last tile (k = k1-8)
        int k = k1 - 8;
#pragma unroll
        for (int b = 0; b < B_; ++b) {
            const float* xb = x + (size_t)b * K + k;
#pragma unroll
            for (int i = 0; i < 8; ++i) {
                float xv = xb[i];
                acc[b].x = fmaf(xv, wv[i].x, acc[b].x);
                acc[b].y = fmaf(xv, wv[i].y, acc[b].y);
                acc[b].z = fmaf(xv, wv[i].z, acc[b].z);
                acc[b].w = fmaf(xv, wv[i].w, acc[b].w);
            }
        }
    }
    float* pp = part + (size_t)blockIdx.y * B_ * N + j0;
#pragma unroll
    for (int b = 0; b < B_; ++b)
        *reinterpret_cast<f32x4*>(pp + (size_t)b * N) = acc[b];  // keep in L2
}

// -------------------------------------------- reduce partials + bias + residual
__global__ __launch_bounds__(256) void reduce_bias_res(
    const float* __restrict__ part, int nsplit, int N,
    const float* __restrict__ bias, const float* __restrict__ res,
    float* __restrict__ out, int total)
{
    int i = blockIdx.x * 256 + threadIdx.x;
    if (i >= total) return;
    float s = 0.f;
    for (int p = 0; p < nsplit; ++p) s += part[(size_t)p * total + i];
    int jc = i % N;
    if (bias) s += bias[jc];
    if (res)  s += res[i];
    out[i] = s;
}

// --------------------------- fused QKV reduce + bias + RoPE (NeoX) + scatter
__global__ __launch_bounds__(256) void qkv_reduce_rope(
    const float* __restrict__ part, int nsplit, const float* __restrict__ bias,
    const int* __restrict__ positions,
    float* __restrict__ q_rot, float* __restrict__ k_rot, float* __restrict__ v_cp)
{
    int b = blockIdx.y;
    int t = threadIdx.x;
    int col = blockIdx.x * 256 + t;
    const int total = B_ * 3 * HID;
    size_t idx = (size_t)b * (3 * HID) + col;
    float s = 0.f;
    for (int p = 0; p < nsplit; ++p) s += part[(size_t)p * total + idx];
    s += bias[col];
    __shared__ float ls[256];
    ls[t] = s;
    __syncthreads();
    int region = col >> 12;          // 0=q, 1=k, 2=v  (HID=4096)
    float outv;
    if (region < 2) {
        int d = col & 127;
        float partner = ls[t ^ 64];  // same head: block base is 256-aligned
        float pos = (float)positions[b];
        float freq = powf(10000.0f, -(float)(d & 63) / 64.0f);
        float sv, cv;
        sincosf(pos * freq, &sv, &cv);
        outv = (d < 64) ? (s * cv - partner * sv) : (s * cv + partner * sv);
    } else {
        outv = s;
    }
    float* dst = (region == 0) ? q_rot : (region == 1) ? k_rot : v_cp;
    dst[(size_t)b * HID + (col & 4095)] = outv;
}

// ------------------------------------- reduce partials of gate_up + fused SwiGLU
__global__ __launch_bounds__(256) void reduce_silu(
    const float* __restrict__ part, int nsplit, float* __restrict__ act)
{
    int i = blockIdx.x * 256 + threadIdx.x;
    if (i >= B_ * INTER) return;
    int b = i / INTER;
    int jc = i - b * INTER;
    size_t off = (size_t)b * (2 * INTER) + jc;
    float g = 0.f, u = 0.f;
    for (int p = 0; p < nsplit; ++p) {
        const float* pp = part + (size_t)p * B_ * 2 * INTER;
        g += pp[off];
        u += pp[off + INTER];
    }
    float sg = g / (1.f + expf(-g));
    act[i] = sg * u;
}

// --------------------------------------------------- split-S decode attention
// (frozen R18 configuration)
__global__ __launch_bounds__(64) void attn_split(
    const float* __restrict__ kc, const float* __restrict__ vc,
    const float* __restrict__ q_rot, const float* __restrict__ k_rot,
    const float* __restrict__ v_cp, const int* __restrict__ positions,
    float* __restrict__ pacc, float* __restrict__ pm, float* __restrict__ pl)
{
    int h = blockIdx.x, b = blockIdx.y, c = blockIdx.z, t = threadIdx.x; // t in [0,64)
    int pos = positions[b];
    int L = pos + 1;
    int j0c = c * CHUNK;
    size_t pidx = (((size_t)b * H_ + h) * NC + c);
    if (j0c >= L) {                 // empty chunk: deterministic zero partials
        if (t == 0) { pm[pidx] = -INFINITY; pl[pidx] = 0.f; }
        pacc[pidx * D_ + t] = 0.f;
        pacc[pidx * D_ + t + 64] = 0.f;
        return;
    }
    int jend = min(L, j0c + CHUNK);
    int jr = t >> 2, q4 = t & 3;    // 4 lanes per key row, 16 rows

    __shared__ float qs[D_];
    __shared__ float ks[TILE * 132];  // padded stride (score reads 2 lanes/bank)
    __shared__ float vs[TILE * D_];
    __shared__ float sc[TILE];

    size_t bh = ((size_t)b * H_ + h) * D_;
    qs[t] = q_rot[bh + t];
    qs[t + 64] = q_rot[bh + t + 64];

    float m = -INFINITY, l = 0.f, a0 = 0.f, a1 = 0.f;
    const float scaling = 0.08838834764831845f;  // 128^-0.5

    for (int j0 = j0c; j0 < jend; j0 += TILE) {
        int nj = min(TILE, jend - j0);
        bool hasPos = (pos >= j0) && (pos < j0 + TILE);
        int rpos = pos - j0;
        __syncthreads();            // single-wave: waitcnt only
        // stage K+V: 16 rows x 32 float4 each; branch-free (rows always < S)
#pragma unroll
        for (int rep = 0; rep < 8; ++rep) {
            int idx = rep * 64 + t;
            int r = idx >> 5, c4 = idx & 31;
            size_t rowoff = (((size_t)b * S_ + (j0 + r)) * H_ + h) * D_;
            float4 kv = reinterpret_cast<const float4*>(kc + rowoff)[c4];
            float4 vv = reinterpret_cast<const float4*>(vc + rowoff)[c4];
            *reinterpret_cast<float4*>(&ks[r * 132 + c4 * 4]) = kv;
            *reinterpret_cast<float4*>(&vs[r * D_  + c4 * 4]) = vv;
        }
        if (hasPos) {               // override pos row from k_rot / v_cp
            if (t < 32) {
                float4 kv = reinterpret_cast<const float4*>(k_rot + bh)[t];
                *reinterpret_cast<float4*>(&ks[rpos * 132 + t * 4]) = kv;
            } else {
                int c4 = t - 32;
                float4 vv = reinterpret_cast<const float4*>(v_cp + bh)[c4];
                *reinterpret_cast<float4*>(&vs[rpos * D_ + c4 * 4]) = vv;
            }
        }
        __syncthreads();
        // scores: stride-4 interleaved dims; K read 2 lanes/bank, Q broadcast
        {
            const float* kr = ks + jr * 132 + q4;
            float s = 0.f;
#pragma unroll
            for (int ci = 0; ci < 32; ++ci) s = fmaf(qs[q4 + 4 * ci], kr[4 * ci], s);
            s += __shfl_xor(s, 1, 64);
            s += __shfl_xor(s, 2, 64);
            if (q4 == 0) sc[jr] = s * scaling;
        }
        __syncthreads();
        // online softmax (registers, static indexing only)
        float p[TILE];
        float mt = m;
#pragma unroll
        for (int r = 0; r < TILE; ++r) {
            float v = (r < nj) ? sc[r] : -INFINITY;
            p[r] = v;
            mt = fmaxf(mt, v);
        }
        float scale = expf(m - mt);
        float ps = 0.f;
#pragma unroll
        for (int r = 0; r < TILE; ++r) {
            float e = (r < nj) ? expf(p[r] - mt) : 0.f;
            p[r] = e;
            ps += e;
        }
        m = mt;
        l = l * scale + ps;
        a0 *= scale;
        a1 *= scale;
#pragma unroll
        for (int r = 0; r < TILE; ++r) {
            a0 = fmaf(p[r], vs[r * D_ + t], a0);
            a1 = fmaf(p[r], vs[r * D_ + t + 64], a1);
        }
    }
    pm[pidx] = m;
    pl[pidx] = l;
    pacc[pidx * D_ + t] = a0;
    pacc[pidx * D_ + t + 64] = a1;
}

// ------------------------------------------------------- combine chunk partials
__global__ __launch_bounds__(128) void attn_combine(
    const float* __restrict__ pacc, const float* __restrict__ pm,
    const float* __restrict__ pl, float* __restrict__ out)
{
    int h = blockIdx.x, b = blockIdx.y, t = threadIdx.x;
    size_t base = ((size_t)b * H_ + h) * NC;
    float M = -INFINITY;
#pragma unroll
    for (int c = 0; c < NC; ++c) M = fmaxf(M, pm[base + c]);
    float l = 0.f, a = 0.f;
#pragma unroll
    for (int c = 0; c < NC; ++c) {
        float w = expf(pm[base + c] - M);
        l = fmaf(pl[base + c], w, l);
        a = fmaf(pacc[(base + c) * D_ + t], w, a);
    }
    out[((size_t)b * H_ + h) * D_ + t] = a / l;
}

// ---------------------------------------------------------------- launcher
extern "C" void kernel_launch(void* const* d_in, const int* in_sizes, int n_in,
                              void* d_out, int out_size, void* d_ws, size_t ws_size,
                              hipStream_t stream)
{
    const int*   positions = (const int*)  d_in[0];
    const float* hidden    = (const float*)d_in[1];
    const float* kc        = (const float*)d_in[2];
    const float* vc        = (const float*)d_in[3];
    const float* qkv_w     = (const float*)d_in[4];
    const float* qkv_b     = (const float*)d_in[5];
    const float* o_w       = (const float*)d_in[6];
    const float* o_b       = (const float*)d_in[7];
    const float* gu_w      = (const float*)d_in[8];
    const float* down_w    = (const float*)d_in[9];
    const float* ln1       = (const float*)d_in[10];
    const float* ln2       = (const float*)d_in[11];
    float* out = (float*)d_out;
    float* ws  = (float*)d_ws;

    float* x1      = ws;                             // 16*4096
    float* q_rot   = x1 + (size_t)B_ * HID;
    float* k_rot   = q_rot + (size_t)B_ * HID;
    float* v_cp    = k_rot + (size_t)B_ * HID;
    float* attn_o  = v_cp + (size_t)B_ * HID;
    float* hidden2 = attn_o + (size_t)B_ * HID;
    float* x2      = hidden2 + (size_t)B_ * HID;
    float* act     = x2 + (size_t)B_ * HID;          // 16*11008
    float* part    = act + (size_t)B_ * INTER;       // partials region

    float* pacc = part;                              // attention overlay (4 MB)
    float* pm   = pacc + (size_t)B_ * H_ * NC * D_;
    float* pl   = pm + (size_t)B_ * H_ * NC;

    // 1. RMSNorm 1
    rmsnorm_kernel<<<B_, 256, 0, stream>>>(hidden, ln1, x1);
    // 2. QKV GEMM (K=4096, N=12288): float4, 12 col-blocks (1024 cols) x 32 splits
    gemm16_splitk4<<<dim3(12, 32), 256, 0, stream>>>(x1, qkv_w, part, HID, 3 * HID, 128);
    // 3. fused reduce + bias + RoPE scatter
    qkv_reduce_rope<<<dim3(48, B_), 256, 0, stream>>>(part, 32, qkv_b, positions,
                                                      q_rot, k_rot, v_cp);
    // 4. split-S decode attention (single-wave blocks, NC=16) + combine
    attn_split<<<dim3(H_, B_, NC), 64, 0, stream>>>(kc, vc, q_rot, k_rot, v_cp, positions,
                                                    pacc, pm, pl);
    attn_combine<<<dim3(H_, B_), 128, 0, stream>>>(pacc, pm, pl, attn_o);
    // 5. O proj (K=4096, N=4096): float2, 8 x 64 (kchunk=64), + residual
    gemm16_splitk2<<<dim3(8, 64), 256, 0, stream>>>(attn_o, o_w, part, HID, HID, 64);
    reduce_bias_res<<<256, 256, 0, stream>>>(part, 64, HID, o_b, hidden, hidden2, B_ * HID);
    // 6. RMSNorm 2
    rmsnorm_kernel<<<B_, 256, 0, stream>>>(hidden2, ln2, x2);
    // 7. gate_up GEMM (K=4096, N=22016): float4, 43 col-blocks (512 cols) x 16 splits
    gemm16_splitk4<<<dim3(43, 16), 128, 0, stream>>>(x2, gu_w, part, HID, 2 * INTER, 256);
    reduce_silu<<<688, 256, 0, stream>>>(part, 16, act);
    // 8. down GEMM (K=11008, N=4096): float2, 8 x 43 (kchunk=256), + residual -> out
    gemm16_splitk2<<<dim3(8, 43), 256, 0, stream>>>(act, down_w, part, INTER, HID, 256);
    reduce_bias_res<<<256, 256, 0, stream>>>(part, 43, HID, nullptr, hidden2, out, B_ * HID);
}

// Round 22
// 286.117 us; speedup vs baseline: 1.0313x; 1.0080x over previous
//
#include <hip/hip_runtime.h>
#include <cstdint>
#include <cmath>

#define B_    16
#define S_    1024
#define H_    32
#define D_    128
#define HID   4096
#define INTER 11008
#define NC    16        // attention sequence chunks
#define CHUNK 64        // S_/NC
#define TILE  16        // K/V rows per staged tile (single-wave block)

typedef float f32x2 __attribute__((ext_vector_type(2)));
typedef float f32x4 __attribute__((ext_vector_type(4)));

// ---------------------------------------------------------------- RMSNorm
__global__ __launch_bounds__(256) void rmsnorm_kernel(
    const float* __restrict__ in, const float* __restrict__ w, float* __restrict__ out)
{
    int b = blockIdx.x;
    int t = threadIdx.x;
    const float4* row = reinterpret_cast<const float4*>(in + (size_t)b * HID);
    float s = 0.f;
    for (int i = t; i < HID / 4; i += 256) {
        float4 v = row[i];
        s += v.x * v.x + v.y * v.y + v.z * v.z + v.w * v.w;
    }
    for (int off = 32; off; off >>= 1) s += __shfl_down(s, off, 64);
    __shared__ float red[4];
    int wid = t >> 6, lane = t & 63;
    if (lane == 0) red[wid] = s;
    __syncthreads();
    float tot = red[0] + red[1] + red[2] + red[3];
    float rstd = rsqrtf(tot / (float)HID + 1e-6f);
    const float4* wv4 = reinterpret_cast<const float4*>(w);
    float4* o4 = reinterpret_cast<float4*>(out + (size_t)b * HID);
    for (int i = t; i < HID / 4; i += 256) {
        float4 x = row[i], wv = wv4[i];
        float4 r;
        r.x = x.x * rstd * wv.x;
        r.y = x.y * rstd * wv.y;
        r.z = x.z * rstd * wv.z;
        r.w = x.w * rstd * wv.w;
        o4[i] = r;
    }
}

// ------------- skinny GEMM, split-K, FLOAT4 cols, register double-buffer
// 16 B/lane nt loads: half the VMEM instruction count of the float2 variant
// at equal in-flight bytes/CU (proven +6us on QKV/gate_up, R21). blockDim-
// parametric: 256-thr blocks span 1024 cols, 128-thr blocks span 512 cols.
// Requires 4 | N, 16 <= kchunk, 8 | kchunk; grids sized exactly.
__global__ __launch_bounds__(256) void gemm16_splitk4(
    const float* __restrict__ x, const float* __restrict__ w,
    float* __restrict__ part, int K, int N, int kchunk)
{
    int j0 = (blockIdx.x * blockDim.x + threadIdx.x) * 4;
    if (j0 >= N) return;                           // safety (grids are exact)
    int k0 = blockIdx.y * kchunk;
    int k1 = k0 + kchunk;
    f32x4 acc[B_];
#pragma unroll
    for (int b = 0; b < B_; ++b) acc[b] = (f32x4)(0.f, 0.f, 0.f, 0.f);

    const float* wp = w + (size_t)k0 * N + j0;
    f32x4 wv[8];
#pragma unroll
    for (int i = 0; i < 8; ++i)                    // prologue: first 8 rows
        wv[i] = __builtin_nontemporal_load(
            reinterpret_cast<const f32x4*>(wp + (size_t)i * N));
    wp += 8 * (size_t)N;

    for (int k = k0; k < k1 - 8; k += 8) {
        f32x4 wn[8];
#pragma unroll
        for (int i = 0; i < 8; ++i)                // issue next tile's nt loads
            wn[i] = __builtin_nontemporal_load(
                reinterpret_cast<const f32x4*>(wp + (size_t)i * N));
        wp += 8 * (size_t)N;
#pragma unroll
        for (int b = 0; b < B_; ++b) {             // FMA on current tile
            const float* xb = x + (size_t)b * K + k;   // wave-uniform -> s_load
#pragma unroll
            for (int i = 0; i < 8; ++i) {
                float xv = xb[i];
                acc[b].x = fmaf(xv, wv[i].x, acc[b].x);
                acc[b].y = fmaf(xv, wv[i].y, acc[b].y);
                acc[b].z = fmaf(xv, wv[i].z, acc[b].z);
                acc[b].w = fmaf(xv, wv[i].w, acc[b].w);
            }
        }
#pragma unroll
        for (int i = 0; i < 8; ++i) wv[i] = wn[i]; // rotate
    }
    {   // epilogue: FMA on the last tile (k = k1-8)
        int k = k1 - 8;
#pragma unroll
        for (int b = 0; b < B_; ++b) {
            const float* xb = x + (size_t)b * K + k;
#pragma unroll
            for (int i = 0; i < 8; ++i) {
                float xv = xb[i];
                acc[b].x = fmaf(xv, wv[i].x, acc[b].x);
                acc[b].y = fmaf(xv, wv[i].y, acc[b].y);
                acc[b].z = fmaf(xv, wv[i].z, acc[b].z);
                acc[b].w = fmaf(xv, wv[i].w, acc[b].w);
            }
        }
    }
    float* pp = part + (size_t)blockIdx.y * B_ * N + j0;
#pragma unroll
    for (int b = 0; b < B_; ++b)
        *reinterpret_cast<f32x4*>(pp + (size_t)b * N) = acc[b];  // keep in L2
}

// -------------------------------------------- reduce partials + bias + residual
__global__ __launch_bounds__(256) void reduce_bias_res(
    const float* __restrict__ part, int nsplit, int N,
    const float* __restrict__ bias, const float* __restrict__ res,
    float* __restrict__ out, int total)
{
    int i = blockIdx.x * 256 + threadIdx.x;
    if (i >= total) return;
    float s = 0.f;
    for (int p = 0; p < nsplit; ++p) s += part[(size_t)p * total + i];
    int jc = i % N;
    if (bias) s += bias[jc];
    if (res)  s += res[i];
    out[i] = s;
}

// --------------------------- fused QKV reduce + bias + RoPE (NeoX) + scatter
__global__ __launch_bounds__(256) void qkv_reduce_rope(
    const float* __restrict__ part, int nsplit, const float* __restrict__ bias,
    const int* __restrict__ positions,
    float* __restrict__ q_rot, float* __restrict__ k_rot, float* __restrict__ v_cp)
{
    int b = blockIdx.y;
    int t = threadIdx.x;
    int col = blockIdx.x * 256 + t;
    const int total = B_ * 3 * HID;
    size_t idx = (size_t)b * (3 * HID) + col;
    float s = 0.f;
    for (int p = 0; p < nsplit; ++p) s += part[(size_t)p * total + idx];
    s += bias[col];
    __shared__ float ls[256];
    ls[t] = s;
    __syncthreads();
    int region = col >> 12;          // 0=q, 1=k, 2=v  (HID=4096)
    float outv;
    if (region < 2) {
        int d = col & 127;
        float partner = ls[t ^ 64];  // same head: block base is 256-aligned
        float pos = (float)positions[b];
        float freq = powf(10000.0f, -(float)(d & 63) / 64.0f);
        float sv, cv;
        sincosf(pos * freq, &sv, &cv);
        outv = (d < 64) ? (s * cv - partner * sv) : (s * cv + partner * sv);
    } else {
        outv = s;
    }
    float* dst = (region == 0) ? q_rot : (region == 1) ? k_rot : v_cp;
    dst[(size_t)b * HID + (col & 4095)] = outv;
}

// ------------------------------------- reduce partials of gate_up + fused SwiGLU
__global__ __launch_bounds__(256) void reduce_silu(
    const float* __restrict__ part, int nsplit, float* __restrict__ act)
{
    int i = blockIdx.x * 256 + threadIdx.x;
    if (i >= B_ * INTER) return;
    int b = i / INTER;
    int jc = i - b * INTER;
    size_t off = (size_t)b * (2 * INTER) + jc;
    float g = 0.f, u = 0.f;
    for (int p = 0; p < nsplit; ++p) {
        const float* pp = part + (size_t)p * B_ * 2 * INTER;
        g += pp[off];
        u += pp[off + INTER];
    }
    float sg = g / (1.f + expf(-g));
    act[i] = sg * u;
}

// --------------------------------------------------- split-S decode attention
// (frozen R18 configuration)
__global__ __launch_bounds__(64) void attn_split(
    const float* __restrict__ kc, const float* __restrict__ vc,
    const float* __restrict__ q_rot, const float* __restrict__ k_rot,
    const float* __restrict__ v_cp, const int* __restrict__ positions,
    float* __restrict__ pacc, float* __restrict__ pm, float* __restrict__ pl)
{
    int h = blockIdx.x, b = blockIdx.y, c = blockIdx.z, t = threadIdx.x; // t in [0,64)
    int pos = positions[b];
    int L = pos + 1;
    int j0c = c * CHUNK;
    size_t pidx = (((size_t)b * H_ + h) * NC + c);
    if (j0c >= L) {                 // empty chunk: deterministic zero partials
        if (t == 0) { pm[pidx] = -INFINITY; pl[pidx] = 0.f; }
        pacc[pidx * D_ + t] = 0.f;
        pacc[pidx * D_ + t + 64] = 0.f;
        return;
    }
    int jend = min(L, j0c + CHUNK);
    int jr = t >> 2, q4 = t & 3;    // 4 lanes per key row, 16 rows

    __shared__ float qs[D_];
    __shared__ float ks[TILE * 132];  // padded stride (score reads 2 lanes/bank)
    __shared__ float vs[TILE * D_];
    __shared__ float sc[TILE];

    size_t bh = ((size_t)b * H_ + h) * D_;
    qs[t] = q_rot[bh + t];
    qs[t + 64] = q_rot[bh + t + 64];

    float m = -INFINITY, l = 0.f, a0 = 0.f, a1 = 0.f;
    const float scaling = 0.08838834764831845f;  // 128^-0.5

    for (int j0 = j0c; j0 < jend; j0 += TILE) {
        int nj = min(TILE, jend - j0);
        bool hasPos = (pos >= j0) && (pos < j0 + TILE);
        int rpos = pos - j0;
        __syncthreads();            // single-wave: waitcnt only
        // stage K+V: 16 rows x 32 float4 each; branch-free (rows always < S)
#pragma unroll
        for (int rep = 0; rep < 8; ++rep) {
            int idx = rep * 64 + t;
            int r = idx >> 5, c4 = idx & 31;
            size_t rowoff = (((size_t)b * S_ + (j0 + r)) * H_ + h) * D_;
            float4 kv = reinterpret_cast<const float4*>(kc + rowoff)[c4];
            float4 vv = reinterpret_cast<const float4*>(vc + rowoff)[c4];
            *reinterpret_cast<float4*>(&ks[r * 132 + c4 * 4]) = kv;
            *reinterpret_cast<float4*>(&vs[r * D_  + c4 * 4]) = vv;
        }
        if (hasPos) {               // override pos row from k_rot / v_cp
            if (t < 32) {
                float4 kv = reinterpret_cast<const float4*>(k_rot + bh)[t];
                *reinterpret_cast<float4*>(&ks[rpos * 132 + t * 4]) = kv;
            } else {
                int c4 = t - 32;
                float4 vv = reinterpret_cast<const float4*>(v_cp + bh)[c4];
                *reinterpret_cast<float4*>(&vs[rpos * D_ + c4 * 4]) = vv;
            }
        }
        __syncthreads();
        // scores: stride-4 interleaved dims; K read 2 lanes/bank, Q broadcast
        {
            const float* kr = ks + jr * 132 + q4;
            float s = 0.f;
#pragma unroll
            for (int ci = 0; ci < 32; ++ci) s = fmaf(qs[q4 + 4 * ci], kr[4 * ci], s);
            s += __shfl_xor(s, 1, 64);
            s += __shfl_xor(s, 2, 64);
            if (q4 == 0) sc[jr] = s * scaling;
        }
        __syncthreads();
        // online softmax (registers, static indexing only)
        float p[TILE];
        float mt = m;
#pragma unroll
        for (int r = 0; r < TILE; ++r) {
            float v = (r < nj) ? sc[r] : -INFINITY;
            p[r] = v;
            mt = fmaxf(mt, v);
        }
        float scale = expf(m - mt);
        float ps = 0.f;
#pragma unroll
        for (int r = 0; r < TILE; ++r) {
            float e = (r < nj) ? expf(p[r] - mt) : 0.f;
            p[r] = e;
            ps += e;
        }
        m = mt;
        l = l * scale + ps;
        a0 *= scale;
        a1 *= scale;
#pragma unroll
        for (int r = 0; r < TILE; ++r) {
            a0 = fmaf(p[r], vs[r * D_ + t], a0);
            a1 = fmaf(p[r], vs[r * D_ + t + 64], a1);
        }
    }
    pm[pidx] = m;
    pl[pidx] = l;
    pacc[pidx * D_ + t] = a0;
    pacc[pidx * D_ + t + 64] = a1;
}

// ------------------------------------------------------- combine chunk partials
__global__ __launch_bounds__(128) void attn_combine(
    const float* __restrict__ pacc, const float* __restrict__ pm,
    const float* __restrict__ pl, float* __restrict__ out)
{
    int h = blockIdx.x, b = blockIdx.y, t = threadIdx.x;
    size_t base = ((size_t)b * H_ + h) * NC;
    float M = -INFINITY;
#pragma unroll
    for (int c = 0; c < NC; ++c) M = fmaxf(M, pm[base + c]);
    float l = 0.f, a = 0.f;
#pragma unroll
    for (int c = 0; c < NC; ++c) {
        float w = expf(pm[base + c] - M);
        l = fmaf(pl[base + c], w, l);
        a = fmaf(pacc[(base + c) * D_ + t], w, a);
    }
    out[((size_t)b * H_ + h) * D_ + t] = a / l;
}

// ---------------------------------------------------------------- launcher
extern "C" void kernel_launch(void* const* d_in, const int* in_sizes, int n_in,
                              void* d_out, int out_size, void* d_ws, size_t ws_size,
                              hipStream_t stream)
{
    const int*   positions = (const int*)  d_in[0];
    const float* hidden    = (const float*)d_in[1];
    const float* kc        = (const float*)d_in[2];
    const float* vc        = (const float*)d_in[3];
    const float* qkv_w     = (const float*)d_in[4];
    const float* qkv_b     = (const float*)d_in[5];
    const float* o_w       = (const float*)d_in[6];
    const float* o_b       = (const float*)d_in[7];
    const float* gu_w      = (const float*)d_in[8];
    const float* down_w    = (const float*)d_in[9];
    const float* ln1       = (const float*)d_in[10];
    const float* ln2       = (const float*)d_in[11];
    float* out = (float*)d_out;
    float* ws  = (float*)d_ws;

    float* x1      = ws;                             // 16*4096
    float* q_rot   = x1 + (size_t)B_ * HID;
    float* k_rot   = q_rot + (size_t)B_ * HID;
    float* v_cp    = k_rot + (size_t)B_ * HID;
    float* attn_o  = v_cp + (size_t)B_ * HID;
    float* hidden2 = attn_o + (size_t)B_ * HID;
    float* x2      = hidden2 + (size_t)B_ * HID;
    float* act     = x2 + (size_t)B_ * HID;          // 16*11008
    float* part    = act + (size_t)B_ * INTER;       // partials region

    float* pacc = part;                              // attention overlay (4 MB)
    float* pm   = pacc + (size_t)B_ * H_ * NC * D_;
    float* pl   = pm + (size_t)B_ * H_ * NC;

    // 1. RMSNorm 1
    rmsnorm_kernel<<<B_, 256, 0, stream>>>(hidden, ln1, x1);
    // 2. QKV GEMM (K=4096, N=12288): float4, 12 col-blocks (1024 cols) x 32 splits
    gemm16_splitk4<<<dim3(12, 32), 256, 0, stream>>>(x1, qkv_w, part, HID, 3 * HID, 128);
    // 3. fused reduce + bias + RoPE scatter
    qkv_reduce_rope<<<dim3(48, B_), 256, 0, stream>>>(part, 32, qkv_b, positions,
                                                      q_rot, k_rot, v_cp);
    // 4. split-S decode attention (single-wave blocks, NC=16) + combine
    attn_split<<<dim3(H_, B_, NC), 64, 0, stream>>>(kc, vc, q_rot, k_rot, v_cp, positions,
                                                    pacc, pm, pl);
    attn_combine<<<dim3(H_, B_), 128, 0, stream>>>(pacc, pm, pl, attn_o);
    // 5. O proj (K=4096, N=4096): float4, 8 col-blocks (512 cols, 128 thr) x 64 splits
    gemm16_splitk4<<<dim3(8, 64), 128, 0, stream>>>(attn_o, o_w, part, HID, HID, 64);
    reduce_bias_res<<<256, 256, 0, stream>>>(part, 64, HID, o_b, hidden, hidden2, B_ * HID);
    // 6. RMSNorm 2
    rmsnorm_kernel<<<B_, 256, 0, stream>>>(hidden2, ln2, x2);
    // 7. gate_up GEMM (K=4096, N=22016): float4, 43 col-blocks (512 cols, 128 thr) x 16
    gemm16_splitk4<<<dim3(43, 16), 128, 0, stream>>>(x2, gu_w, part, HID, 2 * INTER, 256);
    reduce_silu<<<688, 256, 0, stream>>>(part, 16, act);
    // 8. down GEMM (K=11008, N=4096): float4, 8 col-blocks (512 cols, 128 thr) x 43
    gemm16_splitk4<<<dim3(8, 43), 128, 0, stream>>>(act, down_w, part, INTER, HID, 256);
    reduce_bias_res<<<256, 256, 0, stream>>>(part, 43, HID, nullptr, hidden2, out, B_ * HID);
}